// Round 9
// baseline (1845.009 us; speedup 1.0000x reference)
//
#include <hip/hip_runtime.h>
#include <hip/hip_bf16.h>
#include <stdint.h>

#define S_LEN 2048
#define DMODEL 512
#define NH 8
#define DH 64
#define TOPK 32
#define LO_SCALE 4096.0f
#define INV_LO (1.0f/4096.0f)

typedef _Float16 f16;
typedef f16 half8 __attribute__((ext_vector_type(8)));
typedef f16 half4 __attribute__((ext_vector_type(4)));
typedef float floatx4 __attribute__((ext_vector_type(4)));
typedef float f32x4 __attribute__((ext_vector_type(4)));
typedef unsigned long long u64k;

#define AS1 __attribute__((address_space(1)))
#define AS3 __attribute__((address_space(3)))

__device__ __forceinline__ void gl_lds16(const void* g, void* l) {
    __builtin_amdgcn_global_load_lds((const AS1 void*)g, (AS3 void*)l, 16, 0, 0);
}
__device__ __forceinline__ void lds_fence() {
    asm volatile("s_waitcnt lgkmcnt(0)" ::: "memory");
}

// key = sortable(value) in bits [47:16], (0xFFFF - idx) in [15:0]
// -> u64 compare == (value desc, idx asc), identical tie-break to the
// previously passing packed-key scheme.
__device__ __forceinline__ u64k make_key(float f, int idx) {
    unsigned u = __float_as_uint(f);
    unsigned sv = u ^ ((unsigned)(((int)u) >> 31) | 0x80000000u);
    return ((u64k)sv << 16) | (u64k)(0xFFFFu - (unsigned)idx);
}

// ---------------------------------------------------------------------------
// FUSED projections: z<2 = Q/K projection (fp32 vector GEMM,
// SELECTION-CRITICAL, body byte-identical to the passing qkproj: per-output
// fma order k=0..511 ascending, identical staging -> BIT-IDENTICAL Qh/Kh);
// z==2 = V projection (split-fp16 MFMA, selection-irrelevant).  Fusing the
// two independent dispatches into one 768-block launch removes their serial
// execution (~max instead of sum).
// ---------------------------------------------------------------------------
__global__ __launch_bounds__(256)
void proj3(const float* __restrict__ Xq, const float* __restrict__ Xk,
           const float* __restrict__ Xv,
           const float* __restrict__ Wq_, const float* __restrict__ Wk_,
           const f16* __restrict__ WvH, const f16* __restrict__ WvL,
           const float* __restrict__ bq_, const float* __restrict__ bk_,
           const float* __restrict__ bv_,
           float* __restrict__ outQ, float* __restrict__ outK,
           float* __restrict__ outV)
{
    __shared__ __align__(16) char smem[33792];
    const int tid = threadIdx.x;
    const int m0 = blockIdx.y * 128;
    const int n0 = blockIdx.x * 128;

    if (blockIdx.z < 2) {
        // ---------------- Q/K projection (bit-exact fp32) ----------------
        float (*As)[132] = (float(*)[132])smem;              // [k][m]
        float (*Bs)[132] = (float(*)[132])(smem + 16896);    // [k][n]
        const float* X    = blockIdx.z ? Xk  : Xq;
        const float* W    = blockIdx.z ? Wk_ : Wq_;
        const float* bias = blockIdx.z ? bk_ : bq_;
        float* out        = blockIdx.z ? outK : outQ;
        const int tx = tid & 15;
        const int ty = tid >> 4;

        float acc[8][8];
#pragma unroll
        for (int i = 0; i < 8; ++i)
#pragma unroll
            for (int j = 0; j < 8; ++j) acc[i][j] = 0.f;

        f32x4 pa[4], pb[4];
#pragma unroll
        for (int u = 0; u < 4; ++u) {
            int id = tid + u * 256;
            pa[u] = *(const f32x4*)(X + (size_t)(m0 + (id >> 3)) * 512 + (id & 7) * 4);
            pb[u] = *(const f32x4*)(W + (size_t)(id >> 5) * 512 + n0 + (id & 31) * 4);
        }

        for (int k0 = 0; k0 < 512; k0 += 32) {
#pragma unroll
            for (int u = 0; u < 4; ++u) {
                int id = tid + u * 256;
                int r = id >> 3, c4 = (id & 7) * 4;
                As[c4 + 0][r] = pa[u].x; As[c4 + 1][r] = pa[u].y;
                As[c4 + 2][r] = pa[u].z; As[c4 + 3][r] = pa[u].w;
                int rb = id >> 5, cb = (id & 31) * 4;
                *(f32x4*)&Bs[rb][cb] = pb[u];
            }
            __syncthreads();
            if (k0 < 480) {
                int kn = k0 + 32;
#pragma unroll
                for (int u = 0; u < 4; ++u) {
                    int id = tid + u * 256;
                    pa[u] = *(const f32x4*)(X + (size_t)(m0 + (id >> 3)) * 512 + kn + (id & 7) * 4);
                    pb[u] = *(const f32x4*)(W + (size_t)(kn + (id >> 5)) * 512 + n0 + (id & 31) * 4);
                }
            }
#pragma unroll 8
            for (int kk = 0; kk < 32; ++kk) {
                float a[8], b[8];
                *(f32x4*)&a[0] = *(const f32x4*)&As[kk][ty * 4];
                *(f32x4*)&a[4] = *(const f32x4*)&As[kk][64 + ty * 4];
                *(f32x4*)&b[0] = *(const f32x4*)&Bs[kk][tx * 4];
                *(f32x4*)&b[4] = *(const f32x4*)&Bs[kk][64 + tx * 4];
#pragma unroll
                for (int i = 0; i < 8; ++i)
#pragma unroll
                    for (int j = 0; j < 8; ++j)
                        acc[i][j] = fmaf(a[i], b[j], acc[i][j]);
            }
            __syncthreads();
        }

        float bb[8];
        *(f32x4*)&bb[0] = *(const f32x4*)(bias + n0 + tx * 4);
        *(f32x4*)&bb[4] = *(const f32x4*)(bias + n0 + 64 + tx * 4);

#pragma unroll
        for (int i = 0; i < 8; ++i) {
            int r = m0 + ((i >> 2) << 6) + ty * 4 + (i & 3);
            int b_ = r >> 11, s = r & 2047;
#pragma unroll
            for (int h = 0; h < 2; ++h) {
                int c = n0 + h * 64 + tx * 4;
                f32x4 w = {acc[i][h * 4 + 0] + bb[h * 4 + 0],
                           acc[i][h * 4 + 1] + bb[h * 4 + 1],
                           acc[i][h * 4 + 2] + bb[h * 4 + 2],
                           acc[i][h * 4 + 3] + bb[h * 4 + 3]};
                int hd = c >> 6, d = c & 63;
                float* p = out + (((size_t)(b_ * NH + hd) * S_LEN) + s) * DH + d;
                *(f32x4*)p = w;
            }
        }
    } else {
        // ---------------- V projection (split-fp16 MFMA) ------------------
        f16* sm = (f16*)smem;
        f16* As_h = sm;        f16* As_l = sm + 4096;
        f16* Bs_h = sm + 8192; f16* Bs_l = sm + 12288;
        const int lane = tid & 63, wv = tid >> 6;
        const int wm = wv & 1, wn = wv >> 1;
        const int quad = lane >> 4, l15 = lane & 15;

        floatx4 acc_h[4][4], acc_c[4][4];
        const floatx4 z4 = {0.f, 0.f, 0.f, 0.f};
#pragma unroll
        for (int i = 0; i < 4; ++i)
#pragma unroll
            for (int j = 0; j < 4; ++j) { acc_h[i][j] = z4; acc_c[i][j] = z4; }

        for (int k0 = 0; k0 < 512; k0 += 32) {
            __syncthreads();
#pragma unroll
            for (int c = 0; c < 4; ++c) {
                int r   = c * 32 + (tid >> 3);
                int col = (tid & 7) * 4;
                f32x4 x = *(const f32x4*)(Xv + (size_t)(m0 + r) * 512 + k0 + col);
                f16 h0 = (f16)x.x, h1 = (f16)x.y, h2 = (f16)x.z, h3 = (f16)x.w;
                half4 hv = {h0, h1, h2, h3};
                half4 lv = {(f16)((x.x - (float)h0) * LO_SCALE),
                            (f16)((x.y - (float)h1) * LO_SCALE),
                            (f16)((x.z - (float)h2) * LO_SCALE),
                            (f16)((x.w - (float)h3) * LO_SCALE)};
                *(half4*)&As_h[r * 32 + col] = hv;
                *(half4*)&As_l[r * 32 + col] = lv;
            }
#pragma unroll
            for (int c = 0; c < 2; ++c) {
                int r    = c * 64 + (wv << 4) + (lane >> 2);
                int ch   = (lane & 3) * 8;
                int lidx = (c * 64 + (wv << 4)) * 32 + lane * 8;
                gl_lds16(WvH + (size_t)(n0 + r) * 512 + k0 + ch, &Bs_h[lidx]);
                gl_lds16(WvL + (size_t)(n0 + r) * 512 + k0 + ch, &Bs_l[lidx]);
            }
            asm volatile("s_waitcnt vmcnt(0)" ::: "memory");
            __syncthreads();

            half8 bh8[4], bl8[4];
#pragma unroll
            for (int j = 0; j < 4; ++j) {
                int n = wn * 64 + j * 16 + l15;
                bh8[j] = *(const half8*)&Bs_h[n * 32 + quad * 8];
                bl8[j] = *(const half8*)&Bs_l[n * 32 + quad * 8];
            }
#pragma unroll
            for (int i = 0; i < 4; ++i) {
                int m = wm * 64 + i * 16 + l15;
                half8 ah = *(const half8*)&As_h[m * 32 + quad * 8];
                half8 al = *(const half8*)&As_l[m * 32 + quad * 8];
#pragma unroll
                for (int j = 0; j < 4; ++j) {
                    acc_h[i][j] = __builtin_amdgcn_mfma_f32_16x16x32_f16(ah, bh8[j], acc_h[i][j], 0, 0, 0);
                    acc_c[i][j] = __builtin_amdgcn_mfma_f32_16x16x32_f16(ah, bl8[j], acc_c[i][j], 0, 0, 0);
                    acc_c[i][j] = __builtin_amdgcn_mfma_f32_16x16x32_f16(al, bh8[j], acc_c[i][j], 0, 0, 0);
                }
            }
        }

#pragma unroll
        for (int j = 0; j < 4; ++j) {
            int col = n0 + wn * 64 + j * 16 + l15;
            float bv = bv_[col];
#pragma unroll
            for (int i = 0; i < 4; ++i) {
                int rbase = m0 + wm * 64 + i * 16 + quad * 4;
#pragma unroll
                for (int rg = 0; rg < 4; ++rg) {
                    float r = acc_h[i][j][rg] + acc_c[i][j][rg] * INV_LO + bv;
                    int row = rbase + rg;
                    int b_ = row >> 11, s = row & 2047, h = col >> 6, d = col & 63;
                    outV[(((size_t)(b_ * NH + h)) * S_LEN + s) * DH + d] = r;
                }
            }
        }
    }
}

// ---------------------------------------------------------------------------
// FUSED fp32 logits + exact top-32.  SELECTION-CRITICAL invariants:
//  * logits bits: per output, fma chain (d-chunk 0 asc kk, chunk 1 asc kk)
//    with A staged as Q*0.125 -- IDENTICAL ops/order to the passing kernel.
//  * winner set: exact top-32 by key (value desc, idx asc) via batched
//    ballot-append + bitonic sort-32/merge (R8's HW-passed machinery,
//    unchanged; only the tile geometry and slab row formula change).
// R9 GEOMETRY: R8 was jointly VALU+LDS bound (per kk: 128 fma-cyc vs 72
// LDS-cyc -- neither pipe hides the other).  acc[8][16] (q-tile 128 x
// panel 256) makes each kk 256 fma-cyc vs 72 LDS-cyc -> cleanly VALU-bound;
// LDS-read total 205 -> ~123 us; staging & addressing per fma halve.
// Feasible now because batched-merge keys are only 16 u64 = 32 VGPR
// (R3/R4's failure was serial-insert temporaries, not the tile).  No K
// register prefetch (transient staging temps only) -> peak live ~190 VGPR.
// kk-loop LDS reads are broadcast/2-way free; remaining conflicts are the
// once-per-chunk staging writes.  LDS 67072 B (ran on HW in R3) -> 2
// blocks/CU, grid 512 = exactly 2/CU.
// ---------------------------------------------------------------------------
__global__ __launch_bounds__(256)
void logits_topk(const float* __restrict__ Qh, const float* __restrict__ Kh,
                 float* __restrict__ wbuf)
{
    __shared__ float As[2][32][132];               // both d-chunks of 128-row Q tile
    __shared__ __align__(16) char smemB[33280];    // Bs[32][260] floats; slab aliases
    float* Bs = (float*)smemB;                     // Bs[kk*260 + col]
    u64k (*slab)[32] = (u64k(*)[32])smemB;         // [128][32] u64 = 32768 B <= 33280

    const int tid = threadIdx.x;
    const int lig = tid & 15;                 // lane in 16-lane group
    const int ty  = tid >> 4;                 // row-group id (0..15)
    const int gsh = ((tid & 63) >> 4) << 4;   // group's bit-shift in wave ballots
    const unsigned ltg = (1u << lig) - 1u;    // lower-lane mask within group
    const int bh = blockIdx.y;
    const int q0 = blockIdx.x * 128;
    const float* Ab = Qh + (size_t)bh * S_LEN * DH;
    const float* Bb = Kh + (size_t)bh * S_LEN * DH;

    // bitonic sort-32 descending across the group, 2 elems/lane (HW-verified)
    auto sort32 = [&](u64k &a0, u64k &a1) {
#pragma unroll
        for (int s = 2; s <= 32; s <<= 1) {
#pragma unroll
            for (int d = s >> 1; d >= 1; d >>= 1) {
                int e0 = 2 * lig;
                if (d == 1) {
                    bool descB = ((e0 & s) == 0);
                    u64k mx = a0 > a1 ? a0 : a1;
                    u64k mn = a0 > a1 ? a1 : a0;
                    a0 = descB ? mx : mn;
                    a1 = descB ? mn : mx;
                } else {
                    bool descB = ((e0 & s) == 0);
                    bool amS   = ((e0 & d) == 0);
                    bool wantMax = (descB == amS);
                    u64k p0 = __shfl_xor(a0, d >> 1, 16);
                    u64k p1 = __shfl_xor(a1, d >> 1, 16);
                    a0 = wantMax ? (a0 > p0 ? a0 : p0) : (a0 > p0 ? p0 : a0);
                    a1 = wantMax ? (a1 > p1 ? a1 : p1) : (a1 > p1 ? p1 : a1);
                }
            }
        }
    };
    // clean a bitonic 32-sequence to descending (stages d=16..1)
    auto clean32 = [&](u64k &a0, u64k &a1) {
#pragma unroll
        for (int d = 16; d >= 2; d >>= 1) {
            bool amS = (((2 * lig) & d) == 0);
            u64k p0 = __shfl_xor(a0, d >> 1, 16);
            u64k p1 = __shfl_xor(a1, d >> 1, 16);
            a0 = amS ? (a0 > p0 ? a0 : p0) : (a0 > p0 ? p0 : a0);
            a1 = amS ? (a1 > p1 ? a1 : p1) : (a1 > p1 ? p1 : a1);
        }
        u64k mx = a0 > a1 ? a0 : a1;
        u64k mn = a0 > a1 ? a1 : a0;
        a0 = mx; a1 = mn;
    };

    float acc[8][16];
#pragma unroll
    for (int i = 0; i < 8; ++i)
#pragma unroll
        for (int j = 0; j < 16; ++j) acc[i][j] = 0.f;

    u64k key0[8], key1[8], botk[8];
#pragma unroll
    for (int i = 0; i < 8; ++i) { key0[i] = 0; key1[i] = 0; botk[i] = 0; }

    // stage the Q tile once: As[ch][kk][r] = Q[q0+r][ch*32+kk] * 0.125
    // (identical values; visible after the first in-loop barrier)
#pragma unroll
    for (int u = 0; u < 8; ++u) {
        int id = tid + u * 256;
        int r = id >> 4, c4 = (id & 15) * 4;
        int ch = c4 >> 5, cl = c4 & 31;
        f32x4 x = *(const f32x4*)(Ab + (size_t)(q0 + r) * DH + c4);
        As[ch][cl + 0][r] = x.x * 0.125f;
        As[ch][cl + 1][r] = x.y * 0.125f;
        As[ch][cl + 2][r] = x.z * 0.125f;
        As[ch][cl + 3][r] = x.w * 0.125f;
    }

#pragma unroll 1
    for (int kp = 0; kp < 8; ++kp) {
        // ---- GEMM for this 128x256 panel --------------------------------
#pragma unroll
        for (int ch = 0; ch < 2; ++ch) {
            // transient staging temps (NOT live across the kk loop)
            f32x4 kb[8];
#pragma unroll
            for (int u = 0; u < 8; ++u) {
                int id = tid + u * 256;
                int r = id >> 3, c4 = (id & 7) * 4;
                kb[u] = *(const f32x4*)(Bb + (size_t)(kp * 256 + r) * DH + ch * 32 + c4);
            }
            __syncthreads();      // prev Bs/slab users done
#pragma unroll
            for (int u = 0; u < 8; ++u) {
                int id = tid + u * 256;
                int r = id >> 3, c4 = (id & 7) * 4;
                Bs[(c4 + 0) * 260 + r] = kb[u].x;
                Bs[(c4 + 1) * 260 + r] = kb[u].y;
                Bs[(c4 + 2) * 260 + r] = kb[u].z;
                Bs[(c4 + 3) * 260 + r] = kb[u].w;
            }
            __syncthreads();      // Bs (and, first time, As) visible
#pragma unroll 8
            for (int kk = 0; kk < 32; ++kk) {
                float a[8], b[16];
                *(f32x4*)&a[0] = *(const f32x4*)&As[ch][kk][ty * 4];
                *(f32x4*)&a[4] = *(const f32x4*)&As[ch][kk][64 + ty * 4];
#pragma unroll
                for (int h = 0; h < 4; ++h)
                    *(f32x4*)&b[h * 4] = *(const f32x4*)&Bs[kk * 260 + lig * 4 + h * 64];
#pragma unroll
                for (int i = 0; i < 8; ++i)
#pragma unroll
                    for (int j = 0; j < 16; ++j)
                        acc[i][j] = fmaf(a[i], b[j], acc[i][j]);
            }
        }
        __syncthreads();   // ALL waves done reading Bs before slab (alias) writes

        // ---- exact online top-32: batched scan + sort/merge -------------
        // col of acc[i][j] = kp*256 + (j>>2)*64 + lig*4 + (j&3)
        // row_local of acc[i] = (i>>2)*64 + ty*4 + (i&3)
#pragma unroll
        for (int i = 0; i < 8; ++i) {
            const int rl = ((i >> 2) << 6) + ty * 4 + (i & 3);
            unsigned done = 0;
            if (kp == 0) {
                // seed: lane-local top-2 by key, then bitonic sort-32
                u64k t0 = 0, t1 = 0; int j0 = 0, j1 = 0;
#pragma unroll
                for (int j = 0; j < 16; ++j) {
                    u64k kj = make_key(acc[i][j], ((j >> 2) << 6) + (lig << 2) + (j & 3));
                    if (kj > t0)      { t1 = t0; j1 = j0; t0 = kj; j0 = j; }
                    else if (kj > t1) { t1 = kj; j1 = j; }
                }
                key0[i] = t0; key1[i] = t1;
                sort32(key0[i], key1[i]);
                botk[i] = __shfl(key1[i], 15, 16);
                done = (1u << j0) | (1u << j1);
            }
            u64k bk = botk[i];
            int c = 0;
            // <=256 candidates; each overflow pass absorbs 32 -> <=12 passes
#pragma unroll 1
            for (int att = 0; att < 12; ++att) {
                bool ovf = false;
#pragma unroll
                for (int j = 0; j < 16; ++j) {
                    u64k kj = make_key(acc[i][j],
                                       kp * 256 + ((j >> 2) << 6) + (lig << 2) + (j & 3));
                    bool p = (((done >> j) & 1u) == 0u) && (kj > bk);
                    unsigned long long wbm = __ballot(p);
                    unsigned mk = (unsigned)((wbm >> gsh) & 0xFFFFull);
                    if (mk) {
                        int pos = c + __popc(mk & ltg);
                        int tot = c + __popc(mk);
                        if (p && pos < 32) { slab[rl][pos] = kj; done |= 1u << j; }
                        if (tot > 32) { ovf = true; c = 32; } else { c = tot; }
                    }
                }
                bool anyovf = __any(ovf);           // wave-uniform
                if (anyovf) {
                    lds_fence();
                    u64k c0 = (2 * lig     < c) ? slab[rl][2 * lig]     : 0ull;
                    u64k c1 = (2 * lig + 1 < c) ? slab[rl][2 * lig + 1] : 0ull;
                    sort32(c0, c1);
                    u64k m0 = __shfl_xor(c1, 15, 16);
                    u64k m1 = __shfl_xor(c0, 15, 16);
                    key0[i] = key0[i] > m0 ? key0[i] : m0;
                    key1[i] = key1[i] > m1 ? key1[i] : m1;
                    clean32(key0[i], key1[i]);
                    bk = __shfl(key1[i], 15, 16);
                    c = 0;
                } else {
                    break;
                }
            }
            // final merge for this panel (slab dies at next barrier);
            // unconditional -> wave-uniform; c==0 groups merge zero-keys
            {
                lds_fence();
                u64k c0 = (2 * lig     < c) ? slab[rl][2 * lig]     : 0ull;
                u64k c1 = (2 * lig + 1 < c) ? slab[rl][2 * lig + 1] : 0ull;
                sort32(c0, c1);
                u64k m0 = __shfl_xor(c1, 15, 16);
                u64k m1 = __shfl_xor(c0, 15, 16);
                key0[i] = key0[i] > m0 ? key0[i] : m0;
                key1[i] = key1[i] > m1 ? key1[i] : m1;
                clean32(key0[i], key1[i]);
                bk = __shfl(key1[i], 15, 16);
            }
            botk[i] = bk;
        }

        // reset accumulators for the next panel (keys hold the result)
#pragma unroll
        for (int i = 0; i < 8; ++i)
#pragma unroll
            for (int j = 0; j < 16; ++j) acc[i][j] = 0.f;
    }

    // ---- dump winners: 32 sorted keys into the row's own w row ----------
#pragma unroll
    for (int i = 0; i < 8; ++i) {
        int r = q0 + ((i >> 2) << 6) + ty * 4 + (i & 3);
        float* wr = wbuf + ((size_t)bh * S_LEN + r) * S_LEN;
        *(u64k*)(wr + (lig << 2))     = key0[i];   // slot 2*lig
        *(u64k*)(wr + (lig << 2) + 2) = key1[i];   // slot 2*lig+1
    }
}

// ---------------------------------------------------------------------------
// Weight transpose + fp16 hi/lo split for Wv (z=0) and Wo (z=1) only.
// ---------------------------------------------------------------------------
__global__ __launch_bounds__(256)
void wsplit2(const float* __restrict__ W0, const float* __restrict__ W1,
             f16* __restrict__ planes)
{
    __shared__ float tile[32][33];
    const float* W = blockIdx.z ? W1 : W0;
    f16* Th = planes + (size_t)blockIdx.z * 524288;
    f16* Tl = Th + 262144;
    const int bx = blockIdx.x * 32;
    const int by = blockIdx.y * 32;
    const int lx = threadIdx.x & 31, ly = threadIdx.x >> 5;
#pragma unroll
    for (int r = ly; r < 32; r += 8)
        tile[r][lx] = W[(size_t)(by + r) * 512 + bx + lx];
    __syncthreads();
#pragma unroll
    for (int r = ly; r < 32; r += 8) {
        float x = tile[lx][r];              // = W[by+lx][bx+r]
        f16 h = (f16)x;
        f16 l = (f16)((x - (float)h) * LO_SCALE);
        Th[(size_t)(bx + r) * 512 + by + lx] = h;
        Tl[(size_t)(bx + r) * 512 + by + lx] = l;
    }
}

// ---------------------------------------------------------------------------
// Split-fp16 MFMA GEMM, both operands pre-split planes [row][k].
// mode 2: out-proj (K=512, C = A@B^T + bias, fp32 [8192][512]).
// ---------------------------------------------------------------------------
__global__ __launch_bounds__(256)
void gemm_x16(const f16* __restrict__ Ah_, const f16* __restrict__ Al_,
              const f16* __restrict__ Bh_, const f16* __restrict__ Bl_,
              const float* __restrict__ bias, float* __restrict__ outF,
              int Ksz, int ldc, int mode)
{
    __shared__ f16 sm[16384];
    f16* As_h = sm;        f16* As_l = sm + 4096;
    f16* Bs_h = sm + 8192; f16* Bs_l = sm + 12288;
    const int tid  = threadIdx.x;
    const int lane = tid & 63, wv = tid >> 6;
    const int wm = wv & 1, wn = wv >> 1;
    const int quad = lane >> 4, l15 = lane & 15;
    const int m0 = blockIdx.y * 128, n0 = blockIdx.x * 128;

    floatx4 acc_h[4][4], acc_c[4][4];
    const floatx4 z4 = {0.f, 0.f, 0.f, 0.f};
#pragma unroll
    for (int i = 0; i < 4; ++i)
#pragma unroll
        for (int j = 0; j < 4; ++j) { acc_h[i][j] = z4; acc_c[i][j] = z4; }

    for (int k0 = 0; k0 < Ksz; k0 += 32) {
        __syncthreads();
#pragma unroll
        for (int c = 0; c < 2; ++c) {
            int r    = c * 64 + (wv << 4) + (lane >> 2);
            int ch   = (lane & 3) * 8;
            int lidx = (c * 64 + (wv << 4)) * 32 + lane * 8;
            gl_lds16(Ah_ + (size_t)(m0 + r) * Ksz + k0 + ch, &As_h[lidx]);
            gl_lds16(Al_ + (size_t)(m0 + r) * Ksz + k0 + ch, &As_l[lidx]);
            gl_lds16(Bh_ + (size_t)(n0 + r) * Ksz + k0 + ch, &Bs_h[lidx]);
            gl_lds16(Bl_ + (size_t)(n0 + r) * Ksz + k0 + ch, &Bs_l[lidx]);
        }
        asm volatile("s_waitcnt vmcnt(0)" ::: "memory");
        __syncthreads();

        half8 bh8[4], bl8[4];
#pragma unroll
        for (int j = 0; j < 4; ++j) {
            int n = wn * 64 + j * 16 + l15;
            bh8[j] = *(const half8*)&Bs_h[n * 32 + quad * 8];
            bl8[j] = *(const half8*)&Bs_l[n * 32 + quad * 8];
        }
#pragma unroll
        for (int i = 0; i < 4; ++i) {
            int m = wm * 64 + i * 16 + l15;
            half8 ah = *(const half8*)&As_h[m * 32 + quad * 8];
            half8 al = *(const half8*)&As_l[m * 32 + quad * 8];
#pragma unroll
            for (int j = 0; j < 4; ++j) {
                acc_h[i][j] = __builtin_amdgcn_mfma_f32_16x16x32_f16(ah, bh8[j], acc_h[i][j], 0, 0, 0);
                acc_c[i][j] = __builtin_amdgcn_mfma_f32_16x16x32_f16(ah, bl8[j], acc_c[i][j], 0, 0, 0);
                acc_c[i][j] = __builtin_amdgcn_mfma_f32_16x16x32_f16(al, bh8[j], acc_c[i][j], 0, 0, 0);
            }
        }
    }

#pragma unroll
    for (int j = 0; j < 4; ++j) {
        int col = n0 + wn * 64 + j * 16 + l15;
        float bv = (mode == 2) ? bias[col] : 0.f;
#pragma unroll
        for (int i = 0; i < 4; ++i) {
            int rbase = m0 + wm * 64 + i * 16 + quad * 4;
#pragma unroll
            for (int rg = 0; rg < 4; ++rg) {
                float r = acc_h[i][j][rg] + acc_c[i][j][rg] * INV_LO;
                int row = rbase + rg;
                outF[(size_t)row * ldc + col] = r + bv;
            }
        }
    }
}

// ---------------------------------------------------------------------------
// Scatter + sparse attention.  One wave per query row.  Reads the row's 32
// pre-ranked winner keys (first 256 B of its own w row, written by
// logits_topk), computes e=exp(v-m) exactly as before (m = rank-0 = row
// max), renormalizes, then zero+scatter+NT-stream of the full w row and the
// 32-term weighted V sum.  No logits re-read, no threshold search.
// ---------------------------------------------------------------------------
__global__ __launch_bounds__(256)
void topk_scatter(float* __restrict__ wbuf, const float* __restrict__ Vh,
                  f16* __restrict__ attH, f16* __restrict__ attL)
{
    __shared__ float wrow[4][2048];
    __shared__ float win_w[4][TOPK];
    __shared__ int   win_i[4][TOPK];

    const int tid  = threadIdx.x;
    const int wv   = tid >> 6;
    const int lane = tid & 63;
    const int row  = blockIdx.x * 4 + wv;       // (b*8+h)*2048 + s
    float* wr = wbuf + (size_t)row * 2048;

    u64k key = 0;
    if (lane < TOPK) key = ((const u64k*)wr)[lane];
    unsigned sv = (unsigned)(key >> 16);
    unsigned fu = (sv & 0x80000000u) ? (sv ^ 0x80000000u) : ~sv;
    float v = __uint_as_float(fu);
    int idx = (int)(0xFFFFu - (unsigned)(key & 0xFFFFull)) & 2047;

    float m = __shfl(v, 0, 64);                 // rank-0 value = row max
    float e = (lane < TOPK) ? __expf(v - m) : 0.f;

    float mysum = e;
#pragma unroll
    for (int off = 32; off > 0; off >>= 1) mysum += __shfl_xor(mysum, off, 64);
    const float rw = 1.f / mysum;

    if (lane < TOPK) { win_w[wv][lane] = e; win_i[wv][lane] = idx; }

    const f32x4 z = {0.f, 0.f, 0.f, 0.f};
#pragma unroll
    for (int t = 0; t < 8; ++t) ((f32x4*)wrow[wv])[t * 64 + lane] = z;
    lds_fence();
    if (lane < TOPK) wrow[wv][win_i[wv][lane]] = win_w[wv][lane] * rw;
    lds_fence();

    // stream the sparse w row out (overwrites the winner-key scratch too)
#pragma unroll
    for (int t = 0; t < 8; ++t)
        __builtin_nontemporal_store(((f32x4*)wrow[wv])[t * 64 + lane],
                                    (f32x4*)(wr + (size_t)(t * 64 + lane) * 4));

    // sparse attention: 32 weighted V rows; lane = head-dim index
    const int bh = row >> 11;
    const float* Vb = Vh + (size_t)bh * S_LEN * DH;
    float acc = 0.f;
#pragma unroll
    for (int j = 0; j < TOPK; ++j) {
        float wj = win_w[wv][j] * rw;
        int   kj = win_i[wv][j];
        acc = fmaf(wj, Vb[(size_t)kj * DH + lane], acc);
    }
    const int b_ = row >> 14;
    const int h  = (row >> 11) & 7;
    const int s  = row & 2047;
    size_t oidx = (((size_t)b_ * S_LEN) + s) * 512 + h * DH + lane;
    f16 hh = (f16)acc;
    attH[oidx] = hh;
    attL[oidx] = (f16)((acc - (float)hh) * LO_SCALE);
}

// ---------------------------------------------------------------------------
extern "C" void kernel_launch(void* const* d_in, const int* in_sizes, int n_in,
                              void* d_out, int out_size, void* d_ws, size_t ws_size,
                              hipStream_t stream) {
    const float* v  = (const float*)d_in[0];
    const float* k  = (const float*)d_in[1];
    const float* q  = (const float*)d_in[2];
    const float* Wq = (const float*)d_in[3];
    const float* bq = (const float*)d_in[4];
    const float* Wk = (const float*)d_in[5];
    const float* bk = (const float*)d_in[6];
    const float* Wv = (const float*)d_in[7];
    const float* bv = (const float*)d_in[8];
    const float* Wo = (const float*)d_in[9];
    const float* bo = (const float*)d_in[10];

    float* out  = (float*)d_out;                    // [4,2048,512]
    float* wout = out + (size_t)4 * S_LEN * 512;    // [4,8,2048,2048] w output

    char* ws = (char*)d_ws;
    float* Vh   = (float*)ws;                       // fp32 [B,H,S,dh], 16 MB
    float* Qh32 = (float*)(ws + 16777216);          // fp32 [B,H,S,dh], 16 MB
    float* Kh32 = (float*)(ws + 33554432);          // fp32 [B,H,S,dh], 16 MB
    f16* WT  = (f16*)(ws + 50331648);               // 4 planes of 512x512, 2 MB
    f16 *WvH = WT,           *WvL = WT + 262144;
    f16 *WoH = WT + 524288,  *WoL = WT + 786432;
    // att planes alias Qh32 (dead after logits_topk): 8 MB + 8 MB
    f16* attH = (f16*)(ws + 16777216);
    f16* attL = (f16*)(ws + 25165824);

    wsplit2<<<dim3(16, 16, 2), 256, 0, stream>>>(Wv, Wo, WT);

    proj3<<<dim3(4, 64, 3), 256, 0, stream>>>(q, k, v, Wq, Wk, WvH, WvL,
                                              bq, bk, bv, Qh32, Kh32, Vh);

    logits_topk<<<dim3(16, 32), 256, 0, stream>>>(Qh32, Kh32, wout);

    topk_scatter<<<16384, 256, 0, stream>>>(wout, Vh, attH, attL);

    gemm_x16<<<dim3(4, 64, 1), 256, 0, stream>>>(attH, attL, WoH, WoL, bo, out, 512, 512, 2);
}

// Round 10
// 1156.830 us; speedup vs baseline: 1.5949x; 1.5949x over previous
//
#include <hip/hip_runtime.h>
#include <hip/hip_bf16.h>
#include <stdint.h>

#define S_LEN 2048
#define DMODEL 512
#define NH 8
#define DH 64
#define TOPK 32
#define LO_SCALE 4096.0f
#define INV_LO (1.0f/4096.0f)

typedef _Float16 f16;
typedef f16 half8 __attribute__((ext_vector_type(8)));
typedef f16 half4 __attribute__((ext_vector_type(4)));
typedef float floatx4 __attribute__((ext_vector_type(4)));
typedef float f32x4 __attribute__((ext_vector_type(4)));
typedef unsigned long long u64k;

#define AS1 __attribute__((address_space(1)))
#define AS3 __attribute__((address_space(3)))

__device__ __forceinline__ void gl_lds16(const void* g, void* l) {
    __builtin_amdgcn_global_load_lds((const AS1 void*)g, (AS3 void*)l, 16, 0, 0);
}
__device__ __forceinline__ void lds_fence() {
    asm volatile("s_waitcnt lgkmcnt(0)" ::: "memory");
}

// key = sortable(value) in bits [47:16], (0xFFFF - idx) in [15:0]
// -> u64 compare == (value desc, idx asc), identical tie-break to the
// previously passing packed-key scheme.
__device__ __forceinline__ u64k make_key(float f, int idx) {
    unsigned u = __float_as_uint(f);
    unsigned sv = u ^ ((unsigned)(((int)u) >> 31) | 0x80000000u);
    return ((u64k)sv << 16) | (u64k)(0xFFFFu - (unsigned)idx);
}

// ---------------------------------------------------------------------------
// Merged Q+K projection, fp32 vector GEMM.  SELECTION-CRITICAL: per-output
// fma order k=0..511 ascending, identical staging values -> BIT-IDENTICAL.
// 128x128 tile (grid 512 = 2 blocks/CU), conflict-free grouped-4 mapping.
// (R8-measured configuration, verbatim.)
// ---------------------------------------------------------------------------
__global__ __launch_bounds__(256)
void qkproj(const float* __restrict__ Xq, const float* __restrict__ Xk,
            const float* __restrict__ Wq_, const float* __restrict__ Wk_,
            const float* __restrict__ bq_, const float* __restrict__ bk_,
            float* __restrict__ outQ, float* __restrict__ outK)
{
    __shared__ float As[32][132];   // [k][m]
    __shared__ float Bs[32][132];   // [k][n]
    const float* X    = blockIdx.z ? Xk  : Xq;
    const float* W    = blockIdx.z ? Wk_ : Wq_;
    const float* bias = blockIdx.z ? bk_ : bq_;
    float* out        = blockIdx.z ? outK : outQ;
    const int tid = threadIdx.x;
    const int tx = tid & 15;
    const int ty = tid >> 4;
    const int m0 = blockIdx.y * 128;
    const int n0 = blockIdx.x * 128;

    float acc[8][8];
#pragma unroll
    for (int i = 0; i < 8; ++i)
#pragma unroll
        for (int j = 0; j < 8; ++j) acc[i][j] = 0.f;

    f32x4 pa[4], pb[4];
#pragma unroll
    for (int u = 0; u < 4; ++u) {
        int id = tid + u * 256;
        pa[u] = *(const f32x4*)(X + (size_t)(m0 + (id >> 3)) * 512 + (id & 7) * 4);
        pb[u] = *(const f32x4*)(W + (size_t)(id >> 5) * 512 + n0 + (id & 31) * 4);
    }

    for (int k0 = 0; k0 < 512; k0 += 32) {
#pragma unroll
        for (int u = 0; u < 4; ++u) {
            int id = tid + u * 256;
            int r = id >> 3, c4 = (id & 7) * 4;
            As[c4 + 0][r] = pa[u].x; As[c4 + 1][r] = pa[u].y;
            As[c4 + 2][r] = pa[u].z; As[c4 + 3][r] = pa[u].w;
            int rb = id >> 5, cb = (id & 31) * 4;
            *(f32x4*)&Bs[rb][cb] = pb[u];
        }
        __syncthreads();
        if (k0 < 480) {
            int kn = k0 + 32;
#pragma unroll
            for (int u = 0; u < 4; ++u) {
                int id = tid + u * 256;
                pa[u] = *(const f32x4*)(X + (size_t)(m0 + (id >> 3)) * 512 + kn + (id & 7) * 4);
                pb[u] = *(const f32x4*)(W + (size_t)(kn + (id >> 5)) * 512 + n0 + (id & 31) * 4);
            }
        }
#pragma unroll 8
        for (int kk = 0; kk < 32; ++kk) {
            float a[8], b[8];
            *(f32x4*)&a[0] = *(const f32x4*)&As[kk][ty * 4];
            *(f32x4*)&a[4] = *(const f32x4*)&As[kk][64 + ty * 4];
            *(f32x4*)&b[0] = *(const f32x4*)&Bs[kk][tx * 4];
            *(f32x4*)&b[4] = *(const f32x4*)&Bs[kk][64 + tx * 4];
#pragma unroll
            for (int i = 0; i < 8; ++i)
#pragma unroll
                for (int j = 0; j < 8; ++j)
                    acc[i][j] = fmaf(a[i], b[j], acc[i][j]);
        }
        __syncthreads();
    }

    float bb[8];
    *(f32x4*)&bb[0] = *(const f32x4*)(bias + n0 + tx * 4);
    *(f32x4*)&bb[4] = *(const f32x4*)(bias + n0 + 64 + tx * 4);

#pragma unroll
    for (int i = 0; i < 8; ++i) {
        int r = m0 + ((i >> 2) << 6) + ty * 4 + (i & 3);
        int b_ = r >> 11, s = r & 2047;
#pragma unroll
        for (int h = 0; h < 2; ++h) {
            int c = n0 + h * 64 + tx * 4;
            f32x4 w = {acc[i][h * 4 + 0] + bb[h * 4 + 0],
                       acc[i][h * 4 + 1] + bb[h * 4 + 1],
                       acc[i][h * 4 + 2] + bb[h * 4 + 2],
                       acc[i][h * 4 + 3] + bb[h * 4 + 3]};
            int hd = c >> 6, d = c & 63;
            float* p = out + (((size_t)(b_ * NH + hd) * S_LEN) + s) * DH + d;
            *(f32x4*)p = w;
        }
    }
}

// ---------------------------------------------------------------------------
// fp32 logits: per (b,h): L = 0.125*Qh @ Kh^T.  SELECTION-CRITICAL: fma
// order (kh chunk asc, kk asc) and 0.125 prescale-at-stage IDENTICAL to the
// passing kernel -> bit-identical logits.  VERBATIM the R1-measured version
// (part of the best measured total 1120 us): 8x16 register tile on a
// 128(q) x 256(k) block tile, grouped-4 conflict-free fragment mapping,
// both chunks register-prefetched, NT stores (read-once scratch).
// ---------------------------------------------------------------------------
__global__ __launch_bounds__(256, 2)
void gemm_logits(const float* __restrict__ Qh, const float* __restrict__ Kh,
                 float* __restrict__ logits)
{
    __shared__ float As[32][132];   // [k][q], 128 rows
    __shared__ float Bs[32][260];   // [k][kcol], 256 rows staged transposed
    const int tid = threadIdx.x;
    const int tx = tid & 15;        // k-col: tx*4 + h*64
    const int ty = tid >> 4;        // q-row: ty*4 + g*64
    const int bh = blockIdx.z;
    const float* Ab = Qh + (size_t)bh * S_LEN * DH;
    const float* Bb = Kh + (size_t)bh * S_LEN * DH;
    const int q0 = blockIdx.y * 128;
    const int k0 = blockIdx.x * 256;

    float acc[8][16];
#pragma unroll
    for (int i = 0; i < 8; ++i)
#pragma unroll
        for (int j = 0; j < 16; ++j) acc[i][j] = 0.f;

    f32x4 qa[4], kb[8];
#pragma unroll
    for (int u = 0; u < 4; ++u) {
        int id = tid + u * 256;
        qa[u] = *(const f32x4*)(Ab + (size_t)(q0 + (id >> 3)) * DH + (id & 7) * 4);
    }
#pragma unroll
    for (int u = 0; u < 8; ++u) {
        int id = tid + u * 256;
        kb[u] = *(const f32x4*)(Bb + (size_t)(k0 + (id >> 3)) * DH + (id & 7) * 4);
    }

    for (int ch = 0; ch < 2; ++ch) {
#pragma unroll
        for (int u = 0; u < 4; ++u) {
            int id = tid + u * 256;
            int r = id >> 3, c4 = (id & 7) * 4;
            As[c4 + 0][r] = qa[u].x * 0.125f; As[c4 + 1][r] = qa[u].y * 0.125f;
            As[c4 + 2][r] = qa[u].z * 0.125f; As[c4 + 3][r] = qa[u].w * 0.125f;
        }
#pragma unroll
        for (int u = 0; u < 8; ++u) {
            int id = tid + u * 256;
            int r = id >> 3, c4 = (id & 7) * 4;
            Bs[c4 + 0][r] = kb[u].x; Bs[c4 + 1][r] = kb[u].y;
            Bs[c4 + 2][r] = kb[u].z; Bs[c4 + 3][r] = kb[u].w;
        }
        __syncthreads();
        if (ch == 0) {
#pragma unroll
            for (int u = 0; u < 4; ++u) {
                int id = tid + u * 256;
                qa[u] = *(const f32x4*)(Ab + (size_t)(q0 + (id >> 3)) * DH + 32 + (id & 7) * 4);
            }
#pragma unroll
            for (int u = 0; u < 8; ++u) {
                int id = tid + u * 256;
                kb[u] = *(const f32x4*)(Bb + (size_t)(k0 + (id >> 3)) * DH + 32 + (id & 7) * 4);
            }
        }
#pragma unroll 8
        for (int kk = 0; kk < 32; ++kk) {
            float a[8], b[16];
            *(f32x4*)&a[0] = *(const f32x4*)&As[kk][ty * 4];
            *(f32x4*)&a[4] = *(const f32x4*)&As[kk][64 + ty * 4];
#pragma unroll
            for (int h = 0; h < 4; ++h)
                *(f32x4*)&b[h * 4] = *(const f32x4*)&Bs[kk][tx * 4 + h * 64];
#pragma unroll
            for (int i = 0; i < 8; ++i)
#pragma unroll
                for (int j = 0; j < 16; ++j)
                    acc[i][j] = fmaf(a[i], b[j], acc[i][j]);
        }
        __syncthreads();
    }

#pragma unroll
    for (int i = 0; i < 8; ++i) {
        int r = q0 + (i >> 2) * 64 + ty * 4 + (i & 3);
        float* C = logits + (size_t)bh * S_LEN * S_LEN + (size_t)r * S_LEN + k0;
#pragma unroll
        for (int h = 0; h < 4; ++h) {
            f32x4 v = {acc[i][h * 4 + 0], acc[i][h * 4 + 1],
                       acc[i][h * 4 + 2], acc[i][h * 4 + 3]};
            __builtin_nontemporal_store(v, (f32x4*)(C + h * 64 + tx * 4));
        }
    }
}

// ---------------------------------------------------------------------------
// Weight transpose + fp16 hi/lo split for Wv (z=0) and Wo (z=1) only.
// ---------------------------------------------------------------------------
__global__ __launch_bounds__(256)
void wsplit2(const float* __restrict__ W0, const float* __restrict__ W1,
             f16* __restrict__ planes)
{
    __shared__ float tile[32][33];
    const float* W = blockIdx.z ? W1 : W0;
    f16* Th = planes + (size_t)blockIdx.z * 524288;
    f16* Tl = Th + 262144;
    const int bx = blockIdx.x * 32;
    const int by = blockIdx.y * 32;
    const int lx = threadIdx.x & 31, ly = threadIdx.x >> 5;
#pragma unroll
    for (int r = ly; r < 32; r += 8)
        tile[r][lx] = W[(size_t)(by + r) * 512 + bx + lx];
    __syncthreads();
#pragma unroll
    for (int r = ly; r < 32; r += 8) {
        float x = tile[lx][r];              // = W[by+lx][bx+r]
        f16 h = (f16)x;
        f16 l = (f16)((x - (float)h) * LO_SCALE);
        Th[(size_t)(bx + r) * 512 + by + lx] = h;
        Tl[(size_t)(bx + r) * 512 + by + lx] = l;
    }
}

// ---------------------------------------------------------------------------
// Split-fp16 MFMA GEMM, A fp32 (in-kernel split): V projection only
// (selection-irrelevant).  mode 1 = fp32 head-split write.
// ---------------------------------------------------------------------------
__global__ __launch_bounds__(256)
void gemm_x32(const float* __restrict__ X,
              const f16* __restrict__ Bh_, const f16* __restrict__ Bl_,
              const float* __restrict__ bias, float* __restrict__ outF, int mode)
{
    __shared__ f16 sm[16384];
    f16* As_h = sm;       f16* As_l = sm + 4096;
    f16* Bs_h = sm + 8192; f16* Bs_l = sm + 12288;
    const int tid  = threadIdx.x;
    const int lane = tid & 63, wv = tid >> 6;
    const int wm = wv & 1, wn = wv >> 1;
    const int quad = lane >> 4, l15 = lane & 15;
    const int m0 = blockIdx.y * 128, n0 = blockIdx.x * 128;

    floatx4 acc_h[4][4], acc_c[4][4];
    const floatx4 z4 = {0.f, 0.f, 0.f, 0.f};
#pragma unroll
    for (int i = 0; i < 4; ++i)
#pragma unroll
        for (int j = 0; j < 4; ++j) { acc_h[i][j] = z4; acc_c[i][j] = z4; }

    for (int k0 = 0; k0 < 512; k0 += 32) {
        __syncthreads();
#pragma unroll
        for (int c = 0; c < 4; ++c) {
            int r   = c * 32 + (tid >> 3);
            int col = (tid & 7) * 4;
            f32x4 x = *(const f32x4*)(X + (size_t)(m0 + r) * 512 + k0 + col);
            f16 h0 = (f16)x.x, h1 = (f16)x.y, h2 = (f16)x.z, h3 = (f16)x.w;
            half4 hv = {h0, h1, h2, h3};
            half4 lv = {(f16)((x.x - (float)h0) * LO_SCALE),
                        (f16)((x.y - (float)h1) * LO_SCALE),
                        (f16)((x.z - (float)h2) * LO_SCALE),
                        (f16)((x.w - (float)h3) * LO_SCALE)};
            *(half4*)&As_h[r * 32 + col] = hv;
            *(half4*)&As_l[r * 32 + col] = lv;
        }
#pragma unroll
        for (int c = 0; c < 2; ++c) {
            int r    = c * 64 + (wv << 4) + (lane >> 2);
            int ch   = (lane & 3) * 8;
            int lidx = (c * 64 + (wv << 4)) * 32 + lane * 8;
            gl_lds16(Bh_ + (size_t)(n0 + r) * 512 + k0 + ch, &Bs_h[lidx]);
            gl_lds16(Bl_ + (size_t)(n0 + r) * 512 + k0 + ch, &Bs_l[lidx]);
        }
        asm volatile("s_waitcnt vmcnt(0)" ::: "memory");
        __syncthreads();

        half8 bh8[4], bl8[4];
#pragma unroll
        for (int j = 0; j < 4; ++j) {
            int n = wn * 64 + j * 16 + l15;
            bh8[j] = *(const half8*)&Bs_h[n * 32 + quad * 8];
            bl8[j] = *(const half8*)&Bs_l[n * 32 + quad * 8];
        }
#pragma unroll
        for (int i = 0; i < 4; ++i) {
            int m = wm * 64 + i * 16 + l15;
            half8 ah = *(const half8*)&As_h[m * 32 + quad * 8];
            half8 al = *(const half8*)&As_l[m * 32 + quad * 8];
#pragma unroll
            for (int j = 0; j < 4; ++j) {
                acc_h[i][j] = __builtin_amdgcn_mfma_f32_16x16x32_f16(ah, bh8[j], acc_h[i][j], 0, 0, 0);
                acc_c[i][j] = __builtin_amdgcn_mfma_f32_16x16x32_f16(ah, bl8[j], acc_c[i][j], 0, 0, 0);
                acc_c[i][j] = __builtin_amdgcn_mfma_f32_16x16x32_f16(al, bh8[j], acc_c[i][j], 0, 0, 0);
            }
        }
    }

#pragma unroll
    for (int j = 0; j < 4; ++j) {
        int col = n0 + wn * 64 + j * 16 + l15;
        float bv = bias[col];
#pragma unroll
        for (int i = 0; i < 4; ++i) {
            int rbase = m0 + wm * 64 + i * 16 + quad * 4;
#pragma unroll
            for (int rg = 0; rg < 4; ++rg) {
                float r = acc_h[i][j][rg] + acc_c[i][j][rg] * INV_LO + bv;
                int row = rbase + rg;
                if (mode == 2) {
                    outF[(size_t)row * 512 + col] = r;
                } else {
                    int b_ = row >> 11, s = row & 2047, h = col >> 6, d = col & 63;
                    outF[(((size_t)(b_ * NH + h)) * S_LEN + s) * DH + d] = r;
                }
            }
        }
    }
}

// ---------------------------------------------------------------------------
// Split-fp16 MFMA GEMM, both operands pre-split planes [row][k].
// mode 2: out-proj (K=512, C = A@B^T + bias, fp32 [8192][512]).
// ---------------------------------------------------------------------------
__global__ __launch_bounds__(256)
void gemm_x16(const f16* __restrict__ Ah_, const f16* __restrict__ Al_,
              const f16* __restrict__ Bh_, const f16* __restrict__ Bl_,
              const float* __restrict__ bias, float* __restrict__ outF,
              int Ksz, int ldc, int mode)
{
    __shared__ f16 sm[16384];
    f16* As_h = sm;        f16* As_l = sm + 4096;
    f16* Bs_h = sm + 8192; f16* Bs_l = sm + 12288;
    const int tid  = threadIdx.x;
    const int lane = tid & 63, wv = tid >> 6;
    const int wm = wv & 1, wn = wv >> 1;
    const int quad = lane >> 4, l15 = lane & 15;
    const int m0 = blockIdx.y * 128, n0 = blockIdx.x * 128;

    floatx4 acc_h[4][4], acc_c[4][4];
    const floatx4 z4 = {0.f, 0.f, 0.f, 0.f};
#pragma unroll
    for (int i = 0; i < 4; ++i)
#pragma unroll
        for (int j = 0; j < 4; ++j) { acc_h[i][j] = z4; acc_c[i][j] = z4; }

    for (int k0 = 0; k0 < Ksz; k0 += 32) {
        __syncthreads();
#pragma unroll
        for (int c = 0; c < 2; ++c) {
            int r    = c * 64 + (wv << 4) + (lane >> 2);
            int ch   = (lane & 3) * 8;
            int lidx = (c * 64 + (wv << 4)) * 32 + lane * 8;
            gl_lds16(Ah_ + (size_t)(m0 + r) * Ksz + k0 + ch, &As_h[lidx]);
            gl_lds16(Al_ + (size_t)(m0 + r) * Ksz + k0 + ch, &As_l[lidx]);
            gl_lds16(Bh_ + (size_t)(n0 + r) * Ksz + k0 + ch, &Bs_h[lidx]);
            gl_lds16(Bl_ + (size_t)(n0 + r) * Ksz + k0 + ch, &Bs_l[lidx]);
        }
        asm volatile("s_waitcnt vmcnt(0)" ::: "memory");
        __syncthreads();

        half8 bh8[4], bl8[4];
#pragma unroll
        for (int j = 0; j < 4; ++j) {
            int n = wn * 64 + j * 16 + l15;
            bh8[j] = *(const half8*)&Bs_h[n * 32 + quad * 8];
            bl8[j] = *(const half8*)&Bs_l[n * 32 + quad * 8];
        }
#pragma unroll
        for (int i = 0; i < 4; ++i) {
            int m = wm * 64 + i * 16 + l15;
            half8 ah = *(const half8*)&As_h[m * 32 + quad * 8];
            half8 al = *(const half8*)&As_l[m * 32 + quad * 8];
#pragma unroll
            for (int j = 0; j < 4; ++j) {
                acc_h[i][j] = __builtin_amdgcn_mfma_f32_16x16x32_f16(ah, bh8[j], acc_h[i][j], 0, 0, 0);
                acc_c[i][j] = __builtin_amdgcn_mfma_f32_16x16x32_f16(ah, bl8[j], acc_c[i][j], 0, 0, 0);
                acc_c[i][j] = __builtin_amdgcn_mfma_f32_16x16x32_f16(al, bh8[j], acc_c[i][j], 0, 0, 0);
            }
        }
    }

#pragma unroll
    for (int j = 0; j < 4; ++j) {
        int col = n0 + wn * 64 + j * 16 + l15;
        float bv = (mode == 2) ? bias[col] : 0.f;
#pragma unroll
        for (int i = 0; i < 4; ++i) {
            int rbase = m0 + wm * 64 + i * 16 + quad * 4;
#pragma unroll
            for (int rg = 0; rg < 4; ++rg) {
                float r = acc_h[i][j][rg] + acc_c[i][j][rg] * INV_LO;
                int row = rbase + rg;
                outF[(size_t)row * ldc + col] = r + bv;
            }
        }
    }
}

// ---------------------------------------------------------------------------
// Top-k + renorm + sparse attention.  One wave per query row.
// R10 SELECTION CORE: replaces R0's threshold binary search (~40 iters x
// 32 ballots = ~1280 serialized ballots/wave) with the HW-proven batched
// machinery: per-lane top-2 seed -> bitonic sort-128 (same verified network,
// width 64) -> running top-32 (2 keys/lane in lanes 0-15) -> ballot-append
// candidates > bk into a wave-private LDS slab -> sort32 + bitonic merge
// (verbatim R7/R8 lambdas).  Exact: bk monotone non-decreasing, done-mask
// guarantees each value appended at most once, values skipped at <=bk can
// never be top-32; pass bound 70 > worst-case 65 -> provably terminating.
// Epilogue (exp/renorm/zero/scatter/NT-stream/sparse-V) verbatim from the
// passing kernels -> w bits and out bits identical.
// ---------------------------------------------------------------------------
__global__ __launch_bounds__(256)
void topk_attn(float* __restrict__ wbuf, const float* __restrict__ Vh,
               f16* __restrict__ attH, f16* __restrict__ attL)
{
    __shared__ float wrow[4][2048];
    __shared__ u64k  slab[4][32];
    __shared__ float win_w[4][TOPK];
    __shared__ int   win_i[4][TOPK];

    const int tid  = threadIdx.x;
    const int wv   = tid >> 6;
    const int lane = tid & 63;
    const int l15  = lane & 15;
    const unsigned long long lt = (1ull << lane) - 1ull;
    const int row = blockIdx.x * 4 + wv;        // (b*8+h)*2048 + s
    float* wr = wbuf + (size_t)row * 2048;

    // sort-32 descending across a 16-lane partition, 2 elems/lane (verbatim)
    auto sort32 = [&](u64k &a0, u64k &a1) {
#pragma unroll
        for (int s = 2; s <= 32; s <<= 1) {
#pragma unroll
            for (int d = s >> 1; d >= 1; d >>= 1) {
                int e0 = 2 * l15;
                if (d == 1) {
                    bool descB = ((e0 & s) == 0);
                    u64k mx = a0 > a1 ? a0 : a1;
                    u64k mn = a0 > a1 ? a1 : a0;
                    a0 = descB ? mx : mn;
                    a1 = descB ? mn : mx;
                } else {
                    bool descB = ((e0 & s) == 0);
                    bool amS   = ((e0 & d) == 0);
                    bool wantMax = (descB == amS);
                    u64k p0 = __shfl_xor(a0, d >> 1, 16);
                    u64k p1 = __shfl_xor(a1, d >> 1, 16);
                    a0 = wantMax ? (a0 > p0 ? a0 : p0) : (a0 > p0 ? p0 : a0);
                    a1 = wantMax ? (a1 > p1 ? a1 : p1) : (a1 > p1 ? p1 : a1);
                }
            }
        }
    };
    auto clean32 = [&](u64k &a0, u64k &a1) {
#pragma unroll
        for (int d = 16; d >= 2; d >>= 1) {
            bool amS = (((2 * l15) & d) == 0);
            u64k p0 = __shfl_xor(a0, d >> 1, 16);
            u64k p1 = __shfl_xor(a1, d >> 1, 16);
            a0 = amS ? (a0 > p0 ? a0 : p0) : (a0 > p0 ? p0 : a0);
            a1 = amS ? (a1 > p1 ? a1 : p1) : (a1 > p1 ? p1 : a1);
        }
        u64k mx = a0 > a1 ? a0 : a1;
        u64k mn = a0 > a1 ? a1 : a0;
        a0 = mx; a1 = mn;
    };
    // sort-128 descending across the wave, 2 elems/lane (same network, w=64)
    auto sort128 = [&](u64k &a0, u64k &a1) {
#pragma unroll
        for (int s = 2; s <= 128; s <<= 1) {
#pragma unroll
            for (int d = s >> 1; d >= 1; d >>= 1) {
                int e0 = 2 * lane;
                if (d == 1) {
                    bool descB = ((e0 & s) == 0);
                    u64k mx = a0 > a1 ? a0 : a1;
                    u64k mn = a0 > a1 ? a1 : a0;
                    a0 = descB ? mx : mn;
                    a1 = descB ? mn : mx;
                } else {
                    bool descB = ((e0 & s) == 0);
                    bool amS   = ((e0 & d) == 0);
                    bool wantMax = (descB == amS);
                    u64k p0 = __shfl_xor(a0, d >> 1, 64);
                    u64k p1 = __shfl_xor(a1, d >> 1, 64);
                    a0 = wantMax ? (a0 > p0 ? a0 : p0) : (a0 > p0 ? p0 : a0);
                    a1 = wantMax ? (a1 > p1 ? a1 : p1) : (a1 > p1 ? p1 : a1);
                }
            }
        }
    };

    // NT-load the row: L[u] = wr[(u>>2)*256 + lane*4 + (u&3)]
    float L[32];
#pragma unroll
    for (int t = 0; t < 8; ++t) {
        f32x4 x = __builtin_nontemporal_load((const f32x4*)(wr + t * 256 + lane * 4));
        L[4 * t + 0] = x.x; L[4 * t + 1] = x.y; L[4 * t + 2] = x.z; L[4 * t + 3] = x.w;
    }

    // zero own w row early (wave-private; ordered vs later scatter by fence)
    const f32x4 z = {0.f, 0.f, 0.f, 0.f};
#pragma unroll
    for (int t = 0; t < 8; ++t) ((f32x4*)wrow[wv])[t * 64 + lane] = z;

    // seed: lane-local top-2 by key (exact order), then wave sort-128
    u64k k0 = 0, k1 = 0; int j0 = 0, j1 = 0;
#pragma unroll
    for (int u = 0; u < 32; ++u) {
        u64k kj = make_key(L[u], ((u >> 2) << 8) + (lane << 2) + (u & 3));
        if (kj > k0)      { k1 = k0; j1 = j0; k0 = kj; j0 = u; }
        else if (kj > k1) { k1 = kj; j1 = u; }
    }
    sort128(k0, k1);     // ranks 2*lane, 2*lane+1; top-32 = lanes 0..15
    u64k bk = __shfl(k1, 15, 64);     // rank-31 key

    unsigned done = (1u << j0) | (1u << j1);   // seeds never re-appended
    int c = 0;
#pragma unroll 1
    for (int att = 0; att < 70; ++att) {
        bool ovf = false;
#pragma unroll 4
        for (int u = 0; u < 32; ++u) {
            u64k kj = make_key(L[u], ((u >> 2) << 8) + (lane << 2) + (u & 3));
            bool p = (((done >> u) & 1u) == 0u) && (kj > bk);
            unsigned long long mk = __ballot(p);
            if (mk) {
                int pos = c + (int)__popcll(mk & lt);
                int tot = c + (int)__popcll(mk);
                if (p && pos < 32) { slab[wv][pos] = kj; done |= 1u << u; }
                if (tot > 32) { ovf = true; c = 32; } else { c = tot; }
            }
        }
        bool anyovf = __any(ovf);           // wave-uniform
        if (anyovf) {
            lds_fence();
            u64k c0 = (2 * l15     < c) ? slab[wv][2 * l15]     : 0ull;
            u64k c1 = (2 * l15 + 1 < c) ? slab[wv][2 * l15 + 1] : 0ull;
            sort32(c0, c1);
            u64k m0 = __shfl_xor(c1, 15, 16);
            u64k m1 = __shfl_xor(c0, 15, 16);
            k0 = k0 > m0 ? k0 : m0;
            k1 = k1 > m1 ? k1 : m1;
            clean32(k0, k1);                // lanes 0..15 hold valid result
            bk = __shfl(k1, 15, 64);
            c = 0;
        } else {
            break;
        }
    }
    // final merge of residual slab (unconditional, wave-uniform; c may be 0)
    {
        lds_fence();
        u64k c0 = (2 * l15     < c) ? slab[wv][2 * l15]     : 0ull;
        u64k c1 = (2 * l15 + 1 < c) ? slab[wv][2 * l15 + 1] : 0ull;
        sort32(c0, c1);
        u64k m0 = __shfl_xor(c1, 15, 16);
        u64k m1 = __shfl_xor(c0, 15, 16);
        k0 = k0 > m0 ? k0 : m0;
        k1 = k1 > m1 ? k1 : m1;
        clean32(k0, k1);
    }

    // publish sorted winners (group 0 holds ranks 0..31)
    if (lane < 16) { slab[wv][2 * lane] = k0; slab[wv][2 * lane + 1] = k1; }
    lds_fence();

    u64k key = (lane < TOPK) ? slab[wv][lane] : 0ull;
    unsigned sv = (unsigned)(key >> 16);
    unsigned fu = (sv & 0x80000000u) ? (sv ^ 0x80000000u) : ~sv;
    float v = __uint_as_float(fu);
    int idx = (int)(0xFFFFu - (unsigned)(key & 0xFFFFull)) & 2047;

    float m = __shfl(v, 0, 64);                 // rank-0 value = row max
    float e = (lane < TOPK) ? __expf(v - m) : 0.f;

    float mysum = e;
#pragma unroll
    for (int off = 32; off > 0; off >>= 1) mysum += __shfl_xor(mysum, off, 64);
    const float rw = 1.f / mysum;

    if (lane < TOPK) { win_w[wv][lane] = e; win_i[wv][lane] = idx; }
    lds_fence();
    if (lane < TOPK) wrow[wv][win_i[wv][lane]] = win_w[wv][lane] * rw;
    lds_fence();

    // stream the sparse w row out with NT stores
#pragma unroll
    for (int t = 0; t < 8; ++t)
        __builtin_nontemporal_store(((f32x4*)wrow[wv])[t * 64 + lane],
                                    (f32x4*)(wr + (size_t)(t * 64 + lane) * 4));

    // sparse attention: 32 weighted V rows; lane = head-dim index
    const int bh = row >> 11;
    const float* Vb = Vh + (size_t)bh * S_LEN * DH;
    float acc = 0.f;
#pragma unroll
    for (int j = 0; j < TOPK; ++j) {
        float wj = win_w[wv][j] * rw;
        int   kj = win_i[wv][j];
        acc = fmaf(wj, Vb[(size_t)kj * DH + lane], acc);
    }
    const int b_ = row >> 14;
    const int h  = (row >> 11) & 7;
    const int s  = row & 2047;
    size_t oidx = (((size_t)b_ * S_LEN) + s) * 512 + h * DH + lane;
    f16 hh = (f16)acc;
    attH[oidx] = hh;
    attL[oidx] = (f16)((acc - (float)hh) * LO_SCALE);
}

// ---------------------------------------------------------------------------
extern "C" void kernel_launch(void* const* d_in, const int* in_sizes, int n_in,
                              void* d_out, int out_size, void* d_ws, size_t ws_size,
                              hipStream_t stream) {
    const float* v  = (const float*)d_in[0];
    const float* k  = (const float*)d_in[1];
    const float* q  = (const float*)d_in[2];
    const float* Wq = (const float*)d_in[3];
    const float* bq = (const float*)d_in[4];
    const float* Wk = (const float*)d_in[5];
    const float* bk = (const float*)d_in[6];
    const float* Wv = (const float*)d_in[7];
    const float* bv = (const float*)d_in[8];
    const float* Wo = (const float*)d_in[9];
    const float* bo = (const float*)d_in[10];

    float* out  = (float*)d_out;                    // [4,2048,512]
    float* wout = out + (size_t)4 * S_LEN * 512;    // [4,8,2048,2048] (logits scratch, then w)

    char* ws = (char*)d_ws;
    float* Vh   = (float*)ws;                       // fp32 [B,H,S,dh], 16 MB
    float* Qh32 = (float*)(ws + 16777216);          // fp32 [B,H,S,dh], 16 MB
    float* Kh32 = (float*)(ws + 33554432);          // fp32 [B,H,S,dh], 16 MB
    f16* WT  = (f16*)(ws + 50331648);               // 4 planes of 512x512, 2 MB
    f16 *WvH = WT,           *WvL = WT + 262144;
    f16 *WoH = WT + 524288,  *WoL = WT + 786432;
    // att planes alias Qh32 (dead after gemm_logits): 8 MB + 8 MB
    f16* attH = (f16*)(ws + 16777216);
    f16* attL = (f16*)(ws + 25165824);

    wsplit2<<<dim3(16, 16, 2), 256, 0, stream>>>(Wv, Wo, WT);

    qkproj<<<dim3(4, 64, 2), 256, 0, stream>>>(q, k, Wq, Wk, bq, bk, Qh32, Kh32);
    gemm_x32<<<dim3(4, 64), 256, 0, stream>>>(v, WvH, WvL, bv, Vh, 1);

    gemm_logits<<<dim3(8, 16, 32), 256, 0, stream>>>(Qh32, Kh32, wout);

    topk_attn<<<16384, 256, 0, stream>>>(wout, Vh, attH, attL);

    gemm_x16<<<dim3(4, 64, 1), 256, 0, stream>>>(attH, attL, WoH, WoL, bo, out, 512, 512, 2);
}